// Round 3
// baseline (85.545 us; speedup 1.0000x reference)
//
#include <hip/hip_runtime.h>

// GaussianImage Cholesky render, tile-culled rasterization.
// N=20000 gaussians, 256x256x3 image, output CHW float32.

#define N_G   20000
#define IMG_H 256
#define IMG_W 256
#define TILE  16
#define TILES_X (IMG_W / TILE)
#define TILES_Y (IMG_H / TILE)
#define CUT_T 18.0f   // sigma cutoff: exp(-18)=1.5e-8, worst-case sum err 3e-4 << 2e-2

// ---------------- preprocess: per-gaussian params + bbox ----------------
__global__ __launch_bounds__(256) void gs_preprocess(
    const float* __restrict__ xyz,   // (N,2)
    const float* __restrict__ chol,  // (N,3)
    const float* __restrict__ fdc,   // (N,3)
    const float* __restrict__ rgbw,  // (N,1)
    float4* __restrict__ bbox,       // (x0, x1, y0, y1)
    float4* __restrict__ p0,         // (cx, cy, ca, cb)
    float4* __restrict__ p1)         // (cc, fr, fg, fb)
{
    int gi = blockIdx.x * 256 + threadIdx.x;
    if (gi >= N_G) return;
    float l1 = chol[3 * gi + 0] + 0.5f;
    float l2 = chol[3 * gi + 1];
    float l3 = chol[3 * gi + 2] + 0.5f;
    float s11 = l1 * l1;
    float s12 = l1 * l2;
    float s22 = l2 * l2 + l3 * l3;
    float det = s11 * s22 - s12 * s12;   // = l1^2 l3^2 > 0
    float inv = 1.0f / det;
    float ca = s22 * inv;
    float cb = -s12 * inv;
    float cc = s11 * inv;
    float cx = 0.5f * (float)IMG_W * (tanhf(xyz[2 * gi + 0]) + 1.0f) - 0.5f;
    float cy = 0.5f * (float)IMG_H * (tanhf(xyz[2 * gi + 1]) + 1.0f) - 0.5f;
    // max |dx| on the sigma<=T ellipse: sqrt(2T * (Q^-1)_xx) = sqrt(2T * s11)
    float rx = sqrtf(2.0f * CUT_T * s11);
    float ry = sqrtf(2.0f * CUT_T * s22);
    float wgt = rgbw[gi];
    bbox[gi] = make_float4(cx - rx, cx + rx, cy - ry, cy + ry);
    p0[gi] = make_float4(cx, cy, ca, cb);
    p1[gi] = make_float4(cc, fdc[3 * gi + 0] * wgt, fdc[3 * gi + 1] * wgt,
                         fdc[3 * gi + 2] * wgt);
}

// ---------------- tile rasterizer ----------------
// grid.x = 256 tiles (16x16 px), grid.y = gaussian slices.
// Each round: 256 threads test 256 gaussians' bboxes vs this tile, compact
// survivors into LDS, then each thread (one pixel) accumulates all survivors.
__global__ __launch_bounds__(256) void gs_tiles(
    const float4* __restrict__ bbox,
    const float4* __restrict__ p0,
    const float4* __restrict__ p1,
    float* __restrict__ partial,   // [slice][3][H][W]
    int g_per_slice)
{
    __shared__ float4 sh0[256];
    __shared__ float4 sh1[256];
    __shared__ int cnt;

    const int tid = threadIdx.x;
    const int tile = blockIdx.x;
    const int slice = blockIdx.y;
    const int tx0 = (tile % TILES_X) * TILE;
    const int ty0 = (tile / TILES_X) * TILE;
    const int px = tx0 + (tid & (TILE - 1));
    const int py = ty0 + (tid >> 4);
    const float pxf = (float)px;
    const float pyf = (float)py;
    const float txmin = (float)tx0, txmax = (float)(tx0 + TILE - 1);
    const float tymin = (float)ty0, tymax = (float)(ty0 + TILE - 1);

    const int g0 = slice * g_per_slice;
    const int g1 = min(N_G, g0 + g_per_slice);

    float ar = 0.0f, ag = 0.0f, ab = 0.0f;

    for (int base = g0; base < g1; base += 256) {
        __syncthreads();              // previous round's LDS reads done
        if (tid == 0) cnt = 0;
        __syncthreads();
        int gi = base + tid;
        if (gi < g1) {
            float4 bb = bbox[gi];     // (x0,x1,y0,y1)
            if (bb.x <= txmax && bb.y >= txmin && bb.z <= tymax && bb.w >= tymin) {
                int slot = atomicAdd(&cnt, 1);
                sh0[slot] = p0[gi];
                sh1[slot] = p1[gi];
            }
        }
        __syncthreads();
        int m = cnt;
        for (int j = 0; j < m; ++j) {
            float4 q0 = sh0[j];       // broadcast read: no bank conflict
            float4 q1 = sh1[j];
            float dx = pxf - q0.x;
            float dy = pyf - q0.y;
            float sigma = 0.5f * (q0.z * dx * dx + q1.x * dy * dy) + q0.w * dx * dy;
            float w = __expf(-fmaxf(sigma, 0.0f));
            ar = fmaf(w, q1.y, ar);
            ag = fmaf(w, q1.z, ag);
            ab = fmaf(w, q1.w, ab);
        }
    }

    const size_t plane = (size_t)IMG_H * IMG_W;
    float* dst = partial + (size_t)slice * 3 * plane + (size_t)py * IMG_W + px;
    dst[0] = ar;
    dst[plane] = ag;
    dst[2 * plane] = ab;
}

// ---------------- reduce slices + clip, CHW output ----------------
__global__ __launch_bounds__(256) void gs_reduce(
    const float* __restrict__ partial, float* __restrict__ out, int slices)
{
    const int total = 3 * IMG_H * IMG_W;
    int i = blockIdx.x * 256 + threadIdx.x;
    if (i >= total) return;
    float s = 0.0f;
    for (int sl = 0; sl < slices; ++sl)
        s += partial[(size_t)sl * total + i];
    out[i] = fminf(fmaxf(s, 0.0f), 1.0f);
}

extern "C" void kernel_launch(void* const* d_in, const int* in_sizes, int n_in,
                              void* d_out, int out_size, void* d_ws, size_t ws_size,
                              hipStream_t stream) {
    const float* xyz  = (const float*)d_in[0];
    const float* chol = (const float*)d_in[1];
    const float* fdc  = (const float*)d_in[2];
    const float* rgbw = (const float*)d_in[3];
    float* out = (float*)d_out;

    char* ws = (char*)d_ws;
    float4* bbox = (float4*)(ws);
    float4* p0   = (float4*)(ws + (size_t)N_G * 16);
    float4* p1   = (float4*)(ws + (size_t)N_G * 32);
    float* partial = (float*)(ws + (size_t)N_G * 48);

    const size_t gbytes = (size_t)N_G * 48;
    const size_t per_slice = (size_t)3 * IMG_H * IMG_W * sizeof(float);
    int slices = 8;
    while (slices > 1 && gbytes + (size_t)slices * per_slice > ws_size)
        slices >>= 1;
    int gps = (N_G + slices - 1) / slices;

    gs_preprocess<<<(N_G + 255) / 256, 256, 0, stream>>>(
        xyz, chol, fdc, rgbw, bbox, p0, p1);
    gs_tiles<<<dim3(TILES_X * TILES_Y, slices), 256, 0, stream>>>(
        bbox, p0, p1, partial, gps);
    gs_reduce<<<(3 * IMG_H * IMG_W + 255) / 256, 256, 0, stream>>>(
        partial, out, slices);
}